// Round 1
// baseline (427.805 us; speedup 1.0000x reference)
//
#include <hip/hip_runtime.h>
#include <hip/hip_bf16.h>
#include <hip/hip_fp16.h>

// 2D DCT-II via two chained f16 MFMA GEMMs:
//   out[b] = C * X[b] * C^T,  C[k][n] = cos(pi*(2n+1)*k/4096)
// GEMM convention: gemm_bt computes OUT = A * B with B supplied TRANSPOSED
// (Bt row-major N x K) so both operands stage into LDS linearly for
// global_load_lds (wave-uniform base + lane*16B, per cdna guide §5).

typedef _Float16 half8 __attribute__((ext_vector_type(8)));
typedef float f32x4 __attribute__((ext_vector_type(4)));
typedef unsigned int uint32;

__device__ __forceinline__ unsigned short f2h_bits(float f) {
  _Float16 h = (_Float16)f;
  return __builtin_bit_cast(unsigned short, h);
}

__device__ __forceinline__ void gload_lds16(const void* g, void* l) {
  __builtin_amdgcn_global_load_lds((__attribute__((address_space(1))) void*)g,
                                   (__attribute__((address_space(3))) void*)l,
                                   16, 0, 0);
}

// ---- X fp32 -> f16 (8 elems/thread, fully vectorized) ----------------------
__global__ __launch_bounds__(256) void f32_to_f16_kernel(
    const float* __restrict__ x, unsigned short* __restrict__ y) {
  size_t i = ((size_t)blockIdx.x * 256 + threadIdx.x) * 8;
  float4 a = *(const float4*)(x + i);
  float4 b = *(const float4*)(x + i + 4);
  uint4 o;
  o.x = f2h_bits(a.x) | ((uint32)f2h_bits(a.y) << 16);
  o.y = f2h_bits(a.z) | ((uint32)f2h_bits(a.w) << 16);
  o.z = f2h_bits(b.x) | ((uint32)f2h_bits(b.y) << 16);
  o.w = f2h_bits(b.z) | ((uint32)f2h_bits(b.w) << 16);
  *(uint4*)(y + i) = o;
}

// ---- cosine matrix C[i][j] = cos(pi*(2j+1)*i/4096), 2048x2048 f16 ----------
__global__ __launch_bounds__(256) void gen_cos_kernel(
    unsigned short* __restrict__ C) {
  int idx = blockIdx.x * 256 + threadIdx.x;
  int i = idx >> 11;
  int j = idx & 2047;
  int t = ((2 * j + 1) * i) & 8191;              // phase mod 2*pi, exact in int
  float arg = (float)t * 7.6699039394282061e-4f; // pi/4096
  C[idx] = f2h_bits(cosf(arg));
}

// ---- m97-structure GEMM: 128x128 tile, BK=32, 4 waves, 16x16x32 f16 MFMA ---
// MODE 0: OUT written TRANSPOSED as f16 into Tt[b][n][m] (for reuse as Bt).
// MODE 1: OUT written row-major fp32 (batched over blockIdx.z).
template <int MODE>
__global__ __launch_bounds__(256) void dct_gemm(
    const unsigned short* __restrict__ A, const unsigned short* __restrict__ Bt,
    void* __restrict__ outp) {
  constexpr int K = 2048, BK = 32, BM = 128, BN = 128;
  __shared__ unsigned short As[BM * BK];  // [m][k] row-major, linear
  __shared__ unsigned short Bs[BN * BK];  // [n][k] row-major, linear

  const int tid = threadIdx.x;
  const int lane = tid & 63;
  const int wave = tid >> 6;
  const int z = blockIdx.z;
  const int bm = blockIdx.y * BM;
  const int bn = blockIdx.x * BN;

  const unsigned short* Ag = A;  // MODE 1: C matrix shared across batches
  const unsigned short* Bg = Bt + (MODE == 1 ? (size_t)z * 4194304 : (size_t)0);

  // staging geometry: each wave-instruction covers 16 rows (4 lanes x 8 elems)
  const int ldrow = wave * 16 + (lane >> 2);  // row within 64-row chunk
  const int ldcol = (lane & 3) * 8;           // k offset within BK
  const int wrow = (wave >> 1) * 64;          // wave's 64x64 output sub-tile
  const int wcol = (wave & 1) * 64;
  const int frc = lane & 15;                  // fragment row (A) / col (B,D)
  const int fk = (lane >> 4) * 8;             // fragment k offset

  f32x4 acc[4][4] = {};

  for (int k0 = 0; k0 < K; k0 += BK) {
#pragma unroll
    for (int i = 0; i < 2; ++i) {
      const int r = i * 64 + ldrow;
      const unsigned short* ga = Ag + (size_t)(bm + r) * K + (k0 + ldcol);
      const unsigned short* gb = Bg + (size_t)(bn + r) * K + (k0 + ldcol);
      gload_lds16(ga, &As[(i * 64 + wave * 16) * BK]);
      gload_lds16(gb, &Bs[(i * 64 + wave * 16) * BK]);
    }
    __syncthreads();

    half8 af[4], bf[4];
#pragma unroll
    for (int m = 0; m < 4; ++m)
      af[m] = *(const half8*)&As[(wrow + m * 16 + frc) * BK + fk];
#pragma unroll
    for (int n = 0; n < 4; ++n)
      bf[n] = *(const half8*)&Bs[(wcol + n * 16 + frc) * BK + fk];
#pragma unroll
    for (int m = 0; m < 4; ++m)
#pragma unroll
      for (int n = 0; n < 4; ++n)
        acc[m][n] =
            __builtin_amdgcn_mfma_f32_16x16x32_f16(af[m], bf[n], acc[m][n], 0, 0, 0);
    __syncthreads();
  }

  // D fragment mapping (verified m89/m91): col = lane&15, row = (lane>>4)*4+i
  if (MODE == 0) {
    unsigned short* Tt = (unsigned short*)outp;
#pragma unroll
    for (int m = 0; m < 4; ++m) {
      const int r = bm + wrow + m * 16 + (lane >> 4) * 4;  // flat row in M=16384
      const int b = r >> 11;
      const int rb = r & 2047;
#pragma unroll
      for (int n = 0; n < 4; ++n) {
        const int cg = bn + wcol + n * 16 + frc;
        uint32 lo = f2h_bits(acc[m][n][0]) | ((uint32)f2h_bits(acc[m][n][1]) << 16);
        uint32 hi = f2h_bits(acc[m][n][2]) | ((uint32)f2h_bits(acc[m][n][3]) << 16);
        *(uint2*)&Tt[(size_t)b * 4194304 + (size_t)cg * 2048 + rb] =
            make_uint2(lo, hi);
      }
    }
  } else {
    float* out = (float*)outp + (size_t)z * 4194304;
#pragma unroll
    for (int m = 0; m < 4; ++m) {
      const int r = bm + wrow + m * 16 + (lane >> 4) * 4;
#pragma unroll
      for (int n = 0; n < 4; ++n) {
        const int cg = bn + wcol + n * 16 + frc;
#pragma unroll
        for (int i = 0; i < 4; ++i)
          out[(size_t)(r + i) * 2048 + cg] = acc[m][n][i];
      }
    }
  }
}

extern "C" void kernel_launch(void* const* d_in, const int* in_sizes, int n_in,
                              void* d_out, int out_size, void* d_ws,
                              size_t ws_size, hipStream_t stream) {
  const float* x = (const float*)d_in[0];
  float* out = (float*)d_out;

  // workspace layout (f16 elements): Xh 33554432 | C 4194304 | Tt 33554432
  unsigned short* Xh = (unsigned short*)d_ws;
  unsigned short* C = Xh + 33554432u;
  unsigned short* Tt = C + 4194304u;

  // 1) X -> f16
  f32_to_f16_kernel<<<16384, 256, 0, stream>>>(x, Xh);
  // 2) cosine matrix
  gen_cos_kernel<<<16384, 256, 0, stream>>>(C);
  // 3) T = X_flat(16384x2048) * C^T  (Bt = C), write T^T f16 into Tt
  dct_gemm<0><<<dim3(16, 128, 1), 256, 0, stream>>>(Xh, C, (void*)Tt);
  // 4) out[b] = C * T[b]  (A = C, Bt = Tt[b]), fp32 row-major
  dct_gemm<1><<<dim3(16, 16, 8), 256, 0, stream>>>(C, Tt, (void*)out);
}

// Round 2
// 334.338 us; speedup vs baseline: 1.2796x; 1.2796x over previous
//
#include <hip/hip_runtime.h>
#include <hip/hip_bf16.h>
#include <hip/hip_fp16.h>

// 2D DCT-II via two chained f16 MFMA GEMMs: out[b] = C * X[b] * C^T.
// GEMM: 256x256 tile, BK=32, 8 waves (2M x 4N), 4-buffer LDS pipeline with
// counted vmcnt(4) boundaries (T3+T4), XOR-swizzled LDS (T2-equivalent),
// setprio around MFMA clusters (T5). Raw s_barrier (no implicit vmcnt drain).

typedef _Float16 half8 __attribute__((ext_vector_type(8)));
typedef float f32x4 __attribute__((ext_vector_type(4)));
typedef unsigned int uint32;

constexpr int GK = 2048;          // GEMM K
constexpr int BK = 32;            // K-step
constexpr int BM = 256, BN = 256; // tile
constexpr int NT = GK / BK;       // 64 K-tiles
constexpr int TILE_E = BM * BK;   // 8192 f16 = 16KB per matrix tile

__device__ __forceinline__ unsigned short f2h_bits(float f) {
  _Float16 h = (_Float16)f;
  return __builtin_bit_cast(unsigned short, h);
}

__device__ __forceinline__ void gload_lds16(const unsigned short* g, unsigned short* l) {
  __builtin_amdgcn_global_load_lds((const __attribute__((address_space(1))) void*)g,
                                   (__attribute__((address_space(3))) void*)l,
                                   16, 0, 0);
}

// Stored f16 index for logical (tile row r, 16B k-slot byte cb) in a 256x32
// tile. Stored rows are 128B (two logical rows); slot swizzle:
//   slot' = ((r&1)<<2 | cb>>4) ^ ((r>>1)&7)
// -> 64-lane b128 fragment reads hit every 4-bank group exactly 8x (minimum).
__device__ __forceinline__ int swz_idx(int r, int cbyte) {
  int b = (r >> 1) * 128 + ((((r & 1) << 6) | cbyte) ^ (((r >> 1) & 7) << 4));
  return b >> 1;
}

// Stage a 256x32 f16 tile from G (row-major, ld=GK) rows [rowbase,+256),
// k [k0,+32) into LDS tile `lds`. LDS dest is LINEAR (wave-uniform base +
// lane*16B); the swizzle is realized by inverse-permuting per-lane global
// source addresses. 2 global_load_lds per thread.
__device__ __forceinline__ void stage_tile(const unsigned short* __restrict__ G,
                                           int rowbase, int k0,
                                           unsigned short* lds, int wave, int lane) {
#pragma unroll
  for (int c = 0; c < 2; ++c) {
    const int p = c * 64 + wave * 8 + (lane >> 3);   // stored 128B row
    const int v = (lane & 7) ^ ((lane >> 3) & 7);    // inverse slot swizzle
    const int r = 2 * (p) + (v >> 2);                // logical tile row
    const int kslot = v & 3;
    const unsigned short* src = G + (size_t)(rowbase + r) * GK + (k0 + kslot * 8);
    unsigned short* dst = lds + (c * 64 + wave * 8) * 64;  // wave-uniform
    gload_lds16(src, dst);
  }
}

// ---- X fp32 -> f16 (8 elems/thread) ----------------------------------------
__global__ __launch_bounds__(256) void f32_to_f16_kernel(
    const float* __restrict__ x, unsigned short* __restrict__ y) {
  size_t i = ((size_t)blockIdx.x * 256 + threadIdx.x) * 8;
  float4 a = *(const float4*)(x + i);
  float4 b = *(const float4*)(x + i + 4);
  uint4 o;
  o.x = f2h_bits(a.x) | ((uint32)f2h_bits(a.y) << 16);
  o.y = f2h_bits(a.z) | ((uint32)f2h_bits(a.w) << 16);
  o.z = f2h_bits(b.x) | ((uint32)f2h_bits(b.y) << 16);
  o.w = f2h_bits(b.z) | ((uint32)f2h_bits(b.w) << 16);
  *(uint4*)(y + i) = o;
}

// ---- cosine matrix C[i][j] = cos(pi*(2j+1)*i/4096), 2048x2048 f16 ----------
__global__ __launch_bounds__(256) void gen_cos_kernel(
    unsigned short* __restrict__ C) {
  int idx = blockIdx.x * 256 + threadIdx.x;
  int i = idx >> 11;
  int j = idx & 2047;
  int t = ((2 * j + 1) * i) & 8191;
  float arg = (float)t * 7.6699039394282061e-4f;  // pi/4096
  C[idx] = f2h_bits(cosf(arg));
}

// ---- pipelined GEMM --------------------------------------------------------
// MODE 0: OUT written TRANSPOSED f16 into Tt[b][n][m]. MODE 1: fp32 row-major.
template <int MODE>
__global__ __launch_bounds__(512) void dct_gemm(
    const unsigned short* __restrict__ A, const unsigned short* __restrict__ Bt,
    void* __restrict__ outp) {
  __shared__ unsigned short As[4 * TILE_E];
  __shared__ unsigned short Bs[4 * TILE_E];

  const int tid = threadIdx.x;
  const int lane = tid & 63;
  const int wave = tid >> 6;   // 0..7
  const int wr = wave >> 2;    // 0..1  (M half)
  const int wc = wave & 3;     // 0..3  (N quarter)
  const int bm = blockIdx.y * BM;
  const int bn = blockIdx.x * BN;
  const int z = blockIdx.z;

  const unsigned short* Ag = A;
  const unsigned short* Bg = Bt + (MODE == 1 ? (size_t)z * 4194304u : (size_t)0);

  const int frc = lane & 15;         // fragment row (A) / col (B,D)
  const int cb = (lane >> 4) << 4;   // k-slot byte

  f32x4 acc[8][4] = {};

  // prologue: stage tiles 0,1 (8 loads/thread); wait oldest 4 (tile 0)
  stage_tile(Ag, bm, 0, &As[0], wave, lane);
  stage_tile(Bg, bn, 0, &Bs[0], wave, lane);
  stage_tile(Ag, bm, BK, &As[TILE_E], wave, lane);
  stage_tile(Bg, bn, BK, &Bs[TILE_E], wave, lane);
  asm volatile("s_waitcnt vmcnt(4)" ::: "memory");
  __builtin_amdgcn_s_barrier();

  for (int t = 0; t < NT; ++t) {
    const unsigned short* at = &As[(t & 3) * TILE_E];
    const unsigned short* bt = &Bs[(t & 3) * TILE_E];
    half8 af[4], bf[4];

    // ---- phase 1: quadrant mh=0 (rows wr*128 + 0..63) ----
#pragma unroll
    for (int m = 0; m < 4; ++m)
      af[m] = *(const half8*)&at[swz_idx(wr * 128 + m * 16 + frc, cb)];
#pragma unroll
    for (int n = 0; n < 4; ++n)
      bf[n] = *(const half8*)&bt[swz_idx(wc * 64 + n * 16 + frc, cb)];
    if (t + 2 < NT)
      stage_tile(Ag, bm, (t + 2) * BK, &As[((t + 2) & 3) * TILE_E], wave, lane);
    asm volatile("" ::: "memory");
    __builtin_amdgcn_s_barrier();
    __builtin_amdgcn_s_setprio(1);
#pragma unroll
    for (int m = 0; m < 4; ++m)
#pragma unroll
      for (int n = 0; n < 4; ++n)
        acc[m][n] = __builtin_amdgcn_mfma_f32_16x16x32_f16(af[m], bf[n], acc[m][n], 0, 0, 0);
    __builtin_amdgcn_s_setprio(0);
    asm volatile("" ::: "memory");
    __builtin_amdgcn_s_barrier();

    // ---- phase 2: quadrant mh=1 (rows wr*128 + 64..127); bf reused ----
#pragma unroll
    for (int m = 0; m < 4; ++m)
      af[m] = *(const half8*)&at[swz_idx(wr * 128 + 64 + m * 16 + frc, cb)];
    if (t + 2 < NT)
      stage_tile(Bg, bn, (t + 2) * BK, &Bs[((t + 2) & 3) * TILE_E], wave, lane);
    // boundary: tile t+1 must be resident after this barrier.
    // in flight: t+1 (4, staged during t-1) + t+2 (4, this tile) = 8.
    if (t < NT - 2)
      asm volatile("s_waitcnt vmcnt(4)" ::: "memory");  // oldest 4 = t+1 done
    else if (t == NT - 2)
      asm volatile("s_waitcnt vmcnt(0)" ::: "memory");  // final drain
    __builtin_amdgcn_s_barrier();
    __builtin_amdgcn_s_setprio(1);
#pragma unroll
    for (int m = 0; m < 4; ++m)
#pragma unroll
      for (int n = 0; n < 4; ++n)
        acc[m + 4][n] =
            __builtin_amdgcn_mfma_f32_16x16x32_f16(af[m], bf[n], acc[m + 4][n], 0, 0, 0);
    __builtin_amdgcn_s_setprio(0);
    asm volatile("" ::: "memory");
    __builtin_amdgcn_s_barrier();
  }

  // ---- epilogue; D mapping: col = lane&15, row = (lane>>4)*4 + i ----
  if (MODE == 0) {
    unsigned short* Tt = (unsigned short*)outp;
#pragma unroll
    for (int mi = 0; mi < 8; ++mi) {
      const int r = bm + wr * 128 + (mi >> 2) * 64 + (mi & 3) * 16 + (lane >> 4) * 4;
      const int b = r >> 11;
      const int rb = r & 2047;
#pragma unroll
      for (int n = 0; n < 4; ++n) {
        const int cg = bn + wc * 64 + n * 16 + frc;
        uint32 lo = f2h_bits(acc[mi][n][0]) | ((uint32)f2h_bits(acc[mi][n][1]) << 16);
        uint32 hi = f2h_bits(acc[mi][n][2]) | ((uint32)f2h_bits(acc[mi][n][3]) << 16);
        *(uint2*)&Tt[(size_t)b * 4194304 + (size_t)cg * 2048 + rb] =
            make_uint2(lo, hi);
      }
    }
  } else {
    float* out = (float*)outp + (size_t)z * 4194304;
#pragma unroll
    for (int mi = 0; mi < 8; ++mi) {
      const int r = bm + wr * 128 + (mi >> 2) * 64 + (mi & 3) * 16 + (lane >> 4) * 4;
#pragma unroll
      for (int n = 0; n < 4; ++n) {
        const int cg = bn + wc * 64 + n * 16 + frc;
#pragma unroll
        for (int i = 0; i < 4; ++i)
          out[(size_t)(r + i) * 2048 + cg] = acc[mi][n][i];
      }
    }
  }
}

extern "C" void kernel_launch(void* const* d_in, const int* in_sizes, int n_in,
                              void* d_out, int out_size, void* d_ws,
                              size_t ws_size, hipStream_t stream) {
  const float* x = (const float*)d_in[0];
  float* out = (float*)d_out;

  // workspace (f16 elems): Xh 33554432 | C 4194304 | Tt 33554432
  unsigned short* Xh = (unsigned short*)d_ws;
  unsigned short* C = Xh + 33554432u;
  unsigned short* Tt = C + 4194304u;

  f32_to_f16_kernel<<<16384, 256, 0, stream>>>(x, Xh);
  gen_cos_kernel<<<16384, 256, 0, stream>>>(C);
  // T = X_flat(16384x2048) * C^T, written transposed f16 into Tt[b][n][m]
  dct_gemm<0><<<dim3(8, 64, 1), 512, 0, stream>>>(Xh, C, (void*)Tt);
  // out[b] = C * T[b], fp32 row-major
  dct_gemm<1><<<dim3(8, 8, 8), 512, 0, stream>>>(C, Tt, (void*)out);
}

// Round 3
// 327.440 us; speedup vs baseline: 1.3065x; 1.0211x over previous
//
#include <hip/hip_runtime.h>
#include <hip/hip_bf16.h>
#include <hip/hip_fp16.h>

// 2D DCT-II via two chained f16 MFMA GEMMs: out[b] = C * X[b] * C^T.
// GEMM: 256x256 tile, BK=32, 8 waves (2M x 4N), 4-buffer LDS ring with
// counted vmcnt(4) boundaries (T3+T4), XOR-swizzled LDS (T2), setprio (T5).
// R3 change: removed both after-MFMA barriers (2 barriers/K-tile, not 4) so
// ds_read/stage windows of one wave overlap MFMA of the other wave per SIMD.
// Hazard proof: MFMA clusters are register-only; LDS WAR distance (stage t+2
// or t+3 vs reads of t-2/t-1) >= 1 barrier; vmcnt(4)+barrier still releases
// tile t+1 for all threads before any thread reads it.

typedef _Float16 half8 __attribute__((ext_vector_type(8)));
typedef float f32x4 __attribute__((ext_vector_type(4)));
typedef unsigned int uint32;

constexpr int GK = 2048;          // GEMM K
constexpr int BK = 32;            // K-step
constexpr int BM = 256, BN = 256; // tile
constexpr int NT = GK / BK;       // 64 K-tiles
constexpr int TILE_E = BM * BK;   // 8192 f16 = 16KB per matrix tile

__device__ __forceinline__ unsigned short f2h_bits(float f) {
  _Float16 h = (_Float16)f;
  return __builtin_bit_cast(unsigned short, h);
}

__device__ __forceinline__ void gload_lds16(const unsigned short* g, unsigned short* l) {
  __builtin_amdgcn_global_load_lds((const __attribute__((address_space(1))) void*)g,
                                   (__attribute__((address_space(3))) void*)l,
                                   16, 0, 0);
}

#define CFENCE asm volatile("" ::: "memory")

// Stored f16 index for logical (tile row r, 16B k-slot byte cb) in a 256x32
// tile. Stored rows are 128B (two logical rows); slot swizzle:
//   slot' = ((r&1)<<2 | cb>>4) ^ ((r>>1)&7)
__device__ __forceinline__ int swz_idx(int r, int cbyte) {
  int b = (r >> 1) * 128 + ((((r & 1) << 6) | cbyte) ^ (((r >> 1) & 7) << 4));
  return b >> 1;
}

// Stage a 256x32 f16 tile; LDS dest LINEAR (wave-uniform base + lane*16B),
// swizzle realized by inverse-permuting per-lane global source addresses.
__device__ __forceinline__ void stage_tile(const unsigned short* __restrict__ G,
                                           int rowbase, int k0,
                                           unsigned short* lds, int wave, int lane) {
#pragma unroll
  for (int c = 0; c < 2; ++c) {
    const int p = c * 64 + wave * 8 + (lane >> 3);   // stored 128B row
    const int v = (lane & 7) ^ ((lane >> 3) & 7);    // inverse slot swizzle
    const int r = 2 * p + (v >> 2);                  // logical tile row
    const int kslot = v & 3;
    const unsigned short* src = G + (size_t)(rowbase + r) * GK + (k0 + kslot * 8);
    unsigned short* dst = lds + (c * 64 + wave * 8) * 64;  // wave-uniform
    gload_lds16(src, dst);
  }
}

// ---- X fp32 -> f16 (8 elems/thread) ----------------------------------------
__global__ __launch_bounds__(256) void f32_to_f16_kernel(
    const float* __restrict__ x, unsigned short* __restrict__ y) {
  size_t i = ((size_t)blockIdx.x * 256 + threadIdx.x) * 8;
  float4 a = *(const float4*)(x + i);
  float4 b = *(const float4*)(x + i + 4);
  uint4 o;
  o.x = f2h_bits(a.x) | ((uint32)f2h_bits(a.y) << 16);
  o.y = f2h_bits(a.z) | ((uint32)f2h_bits(a.w) << 16);
  o.z = f2h_bits(b.x) | ((uint32)f2h_bits(b.y) << 16);
  o.w = f2h_bits(b.z) | ((uint32)f2h_bits(b.w) << 16);
  *(uint4*)(y + i) = o;
}

// ---- cosine matrix C[i][j] = cos(pi*(2j+1)*i/4096), 2048x2048 f16 ----------
__global__ __launch_bounds__(256) void gen_cos_kernel(
    unsigned short* __restrict__ C) {
  int idx = blockIdx.x * 256 + threadIdx.x;
  int i = idx >> 11;
  int j = idx & 2047;
  int t = ((2 * j + 1) * i) & 8191;
  float arg = (float)t * 7.6699039394282061e-4f;  // pi/4096
  C[idx] = f2h_bits(cosf(arg));
}

// ---- pipelined GEMM --------------------------------------------------------
// MODE 0: OUT written TRANSPOSED f16 into Tt[b][n][m]. MODE 1: fp32 row-major.
template <int MODE>
__global__ __launch_bounds__(512) void dct_gemm(
    const unsigned short* __restrict__ A, const unsigned short* __restrict__ Bt,
    void* __restrict__ outp) {
  __shared__ unsigned short As[4 * TILE_E];
  __shared__ unsigned short Bs[4 * TILE_E];

  const int tid = threadIdx.x;
  const int lane = tid & 63;
  const int wave = tid >> 6;   // 0..7
  const int wr = wave >> 2;    // 0..1  (M half)
  const int wc = wave & 3;     // 0..3  (N quarter)
  const int bm = blockIdx.y * BM;
  const int bn = blockIdx.x * BN;
  const int z = blockIdx.z;

  const unsigned short* Ag = A;
  const unsigned short* Bg = Bt + (MODE == 1 ? (size_t)z * 4194304u : (size_t)0);

  const int frc = lane & 15;         // fragment row (A) / col (B,D)
  const int cb = (lane >> 4) << 4;   // k-slot byte

  f32x4 acc[8][4] = {};

  // prologue: stage tiles 0,1 (8 loads/thread); wait oldest 4 (tile 0)
  stage_tile(Ag, bm, 0, &As[0], wave, lane);
  stage_tile(Bg, bn, 0, &Bs[0], wave, lane);
  stage_tile(Ag, bm, BK, &As[TILE_E], wave, lane);
  stage_tile(Bg, bn, BK, &Bs[TILE_E], wave, lane);
  asm volatile("s_waitcnt vmcnt(4)" ::: "memory");
  CFENCE; __builtin_amdgcn_s_barrier(); CFENCE;

  for (int t = 0; t < NT; ++t) {
    const unsigned short* at = &As[(t & 3) * TILE_E];
    const unsigned short* bt = &Bs[(t & 3) * TILE_E];
    half8 af[4], bf[4];

    // ---- phase 1: reads (quadrant mh=0) + stage A(t+2) ----
#pragma unroll
    for (int m = 0; m < 4; ++m)
      af[m] = *(const half8*)&at[swz_idx(wr * 128 + m * 16 + frc, cb)];
#pragma unroll
    for (int n = 0; n < 4; ++n)
      bf[n] = *(const half8*)&bt[swz_idx(wc * 64 + n * 16 + frc, cb)];
    if (t + 2 < NT)
      stage_tile(Ag, bm, (t + 2) * BK, &As[((t + 2) & 3) * TILE_E], wave, lane);
    CFENCE; __builtin_amdgcn_s_barrier(); CFENCE;   // B1 (pacing)
    __builtin_amdgcn_s_setprio(1);
#pragma unroll
    for (int m = 0; m < 4; ++m)
#pragma unroll
      for (int n = 0; n < 4; ++n)
        acc[m][n] = __builtin_amdgcn_mfma_f32_16x16x32_f16(af[m], bf[n], acc[m][n], 0, 0, 0);
    __builtin_amdgcn_s_setprio(0);
    // NO barrier here: MFMA is register-only; next window may overlap.

    // ---- phase 2: reads (quadrant mh=1) + stage B(t+2) + vmcnt boundary ----
#pragma unroll
    for (int m = 0; m < 4; ++m)
      af[m] = *(const half8*)&at[swz_idx(wr * 128 + 64 + m * 16 + frc, cb)];
    if (t + 2 < NT)
      stage_tile(Bg, bn, (t + 2) * BK, &Bs[((t + 2) & 3) * TILE_E], wave, lane);
    // tile t+1 must be resident after this barrier. In flight: t+1 (4) + t+2 (4).
    if (t < NT - 2)
      asm volatile("s_waitcnt vmcnt(4)" ::: "memory");  // oldest 4 = t+1 done
    else if (t == NT - 2)
      asm volatile("s_waitcnt vmcnt(0)" ::: "memory");  // final drain
    CFENCE; __builtin_amdgcn_s_barrier(); CFENCE;   // B2 (release t+1)
    __builtin_amdgcn_s_setprio(1);
#pragma unroll
    for (int m = 0; m < 4; ++m)
#pragma unroll
      for (int n = 0; n < 4; ++n)
        acc[m + 4][n] =
            __builtin_amdgcn_mfma_f32_16x16x32_f16(af[m], bf[n], acc[m + 4][n], 0, 0, 0);
    __builtin_amdgcn_s_setprio(0);
    // NO barrier here: next iteration's reads (tile t+1) are safe after B2.
  }

  // ---- epilogue; D mapping: col = lane&15, row = (lane>>4)*4 + i ----
  if (MODE == 0) {
    unsigned short* Tt = (unsigned short*)outp;
#pragma unroll
    for (int mi = 0; mi < 8; ++mi) {
      const int r = bm + wr * 128 + (mi >> 2) * 64 + (mi & 3) * 16 + (lane >> 4) * 4;
      const int b = r >> 11;
      const int rb = r & 2047;
#pragma unroll
      for (int n = 0; n < 4; ++n) {
        const int cg = bn + wc * 64 + n * 16 + frc;
        uint32 lo = f2h_bits(acc[mi][n][0]) | ((uint32)f2h_bits(acc[mi][n][1]) << 16);
        uint32 hi = f2h_bits(acc[mi][n][2]) | ((uint32)f2h_bits(acc[mi][n][3]) << 16);
        *(uint2*)&Tt[(size_t)b * 4194304 + (size_t)cg * 2048 + rb] =
            make_uint2(lo, hi);
      }
    }
  } else {
    float* out = (float*)outp + (size_t)z * 4194304;
#pragma unroll
    for (int mi = 0; mi < 8; ++mi) {
      const int r = bm + wr * 128 + (mi >> 2) * 64 + (mi & 3) * 16 + (lane >> 4) * 4;
#pragma unroll
      for (int n = 0; n < 4; ++n) {
        const int cg = bn + wc * 64 + n * 16 + frc;
#pragma unroll
        for (int i = 0; i < 4; ++i)
          out[(size_t)(r + i) * 2048 + cg] = acc[mi][n][i];
      }
    }
  }
}

extern "C" void kernel_launch(void* const* d_in, const int* in_sizes, int n_in,
                              void* d_out, int out_size, void* d_ws,
                              size_t ws_size, hipStream_t stream) {
  const float* x = (const float*)d_in[0];
  float* out = (float*)d_out;

  // workspace (f16 elems): Xh 33554432 | C 4194304 | Tt 33554432
  unsigned short* Xh = (unsigned short*)d_ws;
  unsigned short* C = Xh + 33554432u;
  unsigned short* Tt = C + 4194304u;

  f32_to_f16_kernel<<<16384, 256, 0, stream>>>(x, Xh);
  gen_cos_kernel<<<16384, 256, 0, stream>>>(C);
  // T = X_flat(16384x2048) * C^T, written transposed f16 into Tt[b][n][m]
  dct_gemm<0><<<dim3(8, 64, 1), 512, 0, stream>>>(Xh, C, (void*)Tt);
  // out[b] = C * T[b], fp32 row-major
  dct_gemm<1><<<dim3(8, 8, 8), 512, 0, stream>>>(C, Tt, (void*)out);
}

// Round 4
// 229.675 us; speedup vs baseline: 1.8627x; 1.4257x over previous
//
#include <hip/hip_runtime.h>
#include <hip/hip_bf16.h>
#include <hip/hip_fp16.h>

// 2D DCT-II via folded (even/odd) f16 MFMA GEMMs:
//   y[k] = sum_{n<1024} (x[n] + (-1)^k x[2047-n]) * cos(pi*(2n+1)*k/4096)
// Each 2048-DCT = fold(+/-) + two 1024x1024 GEMMs (Ce/Co) -> half the MACs.
// GEMM structure unchanged from R3: 256x256 tile, BK=32, 8 waves, 4-buffer
// LDS ring, counted vmcnt(4), XOR swizzle, setprio, 2 barriers/K-tile.

typedef _Float16 half8 __attribute__((ext_vector_type(8)));
typedef float f32x4 __attribute__((ext_vector_type(4)));
typedef unsigned int uint32;

constexpr int BK = 32;
constexpr int BM = 256, BN = 256;
constexpr int KK = 1024;          // folded GEMM K
constexpr int NT = KK / BK;       // 32 K-tiles
constexpr int TILE_E = BM * BK;   // 8192 f16 = 16KB

__device__ __forceinline__ unsigned short f2h_bits(float f) {
  _Float16 h = (_Float16)f;
  return __builtin_bit_cast(unsigned short, h);
}
__device__ __forceinline__ float h2f(unsigned short u) {
  return (float)__builtin_bit_cast(_Float16, u);
}

__device__ __forceinline__ void gload_lds16(const unsigned short* g, unsigned short* l) {
  __builtin_amdgcn_global_load_lds((const __attribute__((address_space(1))) void*)g,
                                   (__attribute__((address_space(3))) void*)l,
                                   16, 0, 0);
}

#define CFENCE asm volatile("" ::: "memory")

// Stored f16 index for logical (tile row r, 16B k-slot byte cb); stored rows
// are 128B (two logical rows); slot' = ((r&1)<<2 | cb>>4) ^ ((r>>1)&7).
__device__ __forceinline__ int swz_idx(int r, int cbyte) {
  int b = (r >> 1) * 128 + ((((r & 1) << 6) | cbyte) ^ (((r >> 1) & 7) << 4));
  return b >> 1;
}

// Stage a 256x32 f16 tile from G (row-major, stride ld); LDS dest LINEAR,
// swizzle realized by inverse-permuting per-lane global source addresses.
__device__ __forceinline__ void stage_tile(const unsigned short* __restrict__ G,
                                           int rowbase, int k0, int ld,
                                           unsigned short* lds, int wave, int lane) {
#pragma unroll
  for (int c = 0; c < 2; ++c) {
    const int p = c * 64 + wave * 8 + (lane >> 3);   // stored 128B row
    const int v = (lane & 7) ^ ((lane >> 3) & 7);    // inverse slot swizzle
    const int r = 2 * p + (v >> 2);                  // logical tile row
    const int kslot = v & 3;
    const unsigned short* src = G + (size_t)(rowbase + r) * ld + (k0 + kslot * 8);
    unsigned short* dst = lds + (c * 64 + wave * 8) * 64;  // wave-uniform
    gload_lds16(src, dst);
  }
}

// ---- convert + stage-1 fold: Xf[m][n]=x[n]+x[2047-n], Xf[m][1024+n]=diff ---
__global__ __launch_bounds__(256) void cvt_fold1(const float* __restrict__ x,
                                                 unsigned short* __restrict__ Xf) {
  int tid = blockIdx.x * 256 + threadIdx.x;   // 2M threads
  int m = tid >> 7;                           // 16384 rows
  int n0 = (tid & 127) << 3;                  // 0..1016
  const float* row = x + (size_t)m * 2048;
  float4 a = *(const float4*)(row + n0);
  float4 b = *(const float4*)(row + n0 + 4);
  float4 c = *(const float4*)(row + 2040 - n0);
  float4 d = *(const float4*)(row + 2044 - n0);
  float f[8] = {a.x, a.y, a.z, a.w, b.x, b.y, b.z, b.w};
  float g[8] = {d.w, d.z, d.y, d.x, c.w, c.z, c.y, c.x};  // partner of n0+e
  uint32 up[4], um[4];
#pragma unroll
  for (int e = 0; e < 4; ++e) {
    up[e] = f2h_bits(f[2 * e] + g[2 * e]) |
            ((uint32)f2h_bits(f[2 * e + 1] + g[2 * e + 1]) << 16);
    um[e] = f2h_bits(f[2 * e] - g[2 * e]) |
            ((uint32)f2h_bits(f[2 * e + 1] - g[2 * e + 1]) << 16);
  }
  unsigned short* o = Xf + (size_t)m * 2048 + n0;
  *(uint4*)o = make_uint4(up[0], up[1], up[2], up[3]);
  *(uint4*)(o + 1024) = make_uint4(um[0], um[1], um[2], um[3]);
}

// ---- even/odd cosine matrices, 1024x1024 each -------------------------------
// Ce[k][n] = cos(pi*(2n+1)*(2k)/4096), Co[k][n] = cos(pi*(2n+1)*(2k+1)/4096)
__global__ __launch_bounds__(256) void gen_cos2(unsigned short* __restrict__ Ce,
                                                unsigned short* __restrict__ Co) {
  int idx = blockIdx.x * 256 + threadIdx.x;  // 1M
  int k = idx >> 10, n = idx & 1023;
  int tn = 2 * n + 1;
  int pe = (tn * (2 * k)) & 8191;
  int po = (tn * (2 * k + 1)) & 8191;
  const float s = 7.6699039394282061e-4f;  // pi/4096
  Ce[idx] = f2h_bits(cosf((float)pe * s));
  Co[idx] = f2h_bits(cosf((float)po * s));
}

// ---- stage-2 fold along m: U2[row][u]=Tt[u]+Tt[2047-u], [1024+u]=diff -------
__global__ __launch_bounds__(256) void fold2(const unsigned short* __restrict__ Tt,
                                             unsigned short* __restrict__ U2) {
  int tid = blockIdx.x * 256 + threadIdx.x;  // 2M threads
  int row = tid >> 7;                        // b*2048 + k, 16384 rows
  int j = (tid & 127) << 3;
  const unsigned short* p = Tt + (size_t)row * 2048;
  uint4 F = *(const uint4*)(p + j);
  uint4 Bv = *(const uint4*)(p + 2040 - j);
  uint32 fw[4] = {F.x, F.y, F.z, F.w};
  uint32 bw[4] = {Bv.x, Bv.y, Bv.z, Bv.w};
  float fe[8], ge[8];
#pragma unroll
  for (int e = 0; e < 8; ++e) {
    fe[e] = h2f((unsigned short)(fw[e >> 1] >> ((e & 1) * 16)));
    int pi = 7 - e;  // partner element within reversed 8-vector
    ge[e] = h2f((unsigned short)(bw[pi >> 1] >> ((pi & 1) * 16)));
  }
  uint32 up[4], um[4];
#pragma unroll
  for (int e = 0; e < 4; ++e) {
    up[e] = f2h_bits(fe[2 * e] + ge[2 * e]) |
            ((uint32)f2h_bits(fe[2 * e + 1] + ge[2 * e + 1]) << 16);
    um[e] = f2h_bits(fe[2 * e] - ge[2 * e]) |
            ((uint32)f2h_bits(fe[2 * e + 1] - ge[2 * e + 1]) << 16);
  }
  unsigned short* o = U2 + (size_t)row * 2048 + j;
  *(uint4*)o = make_uint4(up[0], up[1], up[2], up[3]);
  *(uint4*)(o + 1024) = make_uint4(um[0], um[1], um[2], um[3]);
}

// ---- pipelined GEMM, K=1024 -------------------------------------------------
// MODE 0: A = Xf (col half by bn), B = Ce/Co; OUT f16 transposed into
//         Tt[b][k_true][m] (k_true = parity-unpacked output col).
// MODE 1: A = Ce/Co (by bm half), B = U2[z] (col half by bm half); OUT fp32
//         row-major at parity-unpacked row.
template <int MODE>
__global__ __launch_bounds__(512) void dct_gemm(
    const unsigned short* __restrict__ Ce, const unsigned short* __restrict__ Co,
    const unsigned short* __restrict__ D, void* __restrict__ outp) {
  __shared__ unsigned short As[4 * TILE_E];
  __shared__ unsigned short Bs[4 * TILE_E];

  const int tid = threadIdx.x;
  const int lane = tid & 63;
  const int wave = tid >> 6;
  const int wr = wave >> 2;
  const int wc = wave & 3;
  const int bm = blockIdx.y * BM;
  const int bn = blockIdx.x * BN;
  const int z = blockIdx.z;

  const unsigned short* Ag;
  const unsigned short* Bg;
  int lda, ldb, arow, brow;
  bool half;
  if (MODE == 0) {
    half = (bn >= 1024);
    Ag = D + (half ? 1024 : 0); lda = 2048; arow = bm;
    Bg = half ? Co : Ce;        ldb = 1024; brow = bn - (half ? 1024 : 0);
  } else {
    half = (bm >= 1024);
    Ag = half ? Co : Ce;        lda = 1024; arow = bm - (half ? 1024 : 0);
    Bg = D + (size_t)z * 4194304u + (half ? 1024 : 0);
    ldb = 2048; brow = bn;
  }

  const int frc = lane & 15;
  const int cb = (lane >> 4) << 4;

  f32x4 acc[8][4] = {};

  stage_tile(Ag, arow, 0, lda, &As[0], wave, lane);
  stage_tile(Bg, brow, 0, ldb, &Bs[0], wave, lane);
  stage_tile(Ag, arow, BK, lda, &As[TILE_E], wave, lane);
  stage_tile(Bg, brow, BK, ldb, &Bs[TILE_E], wave, lane);
  asm volatile("s_waitcnt vmcnt(4)" ::: "memory");
  CFENCE; __builtin_amdgcn_s_barrier(); CFENCE;

  for (int t = 0; t < NT; ++t) {
    const unsigned short* at = &As[(t & 3) * TILE_E];
    const unsigned short* bt = &Bs[(t & 3) * TILE_E];
    half8 af[4], bf[4];

    // phase 1: reads (quadrant mh=0) + stage A(t+2)
#pragma unroll
    for (int m = 0; m < 4; ++m)
      af[m] = *(const half8*)&at[swz_idx(wr * 128 + m * 16 + frc, cb)];
#pragma unroll
    for (int n = 0; n < 4; ++n)
      bf[n] = *(const half8*)&bt[swz_idx(wc * 64 + n * 16 + frc, cb)];
    if (t + 2 < NT)
      stage_tile(Ag, arow, (t + 2) * BK, lda, &As[((t + 2) & 3) * TILE_E], wave, lane);
    CFENCE; __builtin_amdgcn_s_barrier(); CFENCE;
    __builtin_amdgcn_s_setprio(1);
#pragma unroll
    for (int m = 0; m < 4; ++m)
#pragma unroll
      for (int n = 0; n < 4; ++n)
        acc[m][n] = __builtin_amdgcn_mfma_f32_16x16x32_f16(af[m], bf[n], acc[m][n], 0, 0, 0);
    __builtin_amdgcn_s_setprio(0);

    // phase 2: reads (quadrant mh=1) + stage B(t+2) + counted boundary
#pragma unroll
    for (int m = 0; m < 4; ++m)
      af[m] = *(const half8*)&at[swz_idx(wr * 128 + 64 + m * 16 + frc, cb)];
    if (t + 2 < NT)
      stage_tile(Bg, brow, (t + 2) * BK, ldb, &Bs[((t + 2) & 3) * TILE_E], wave, lane);
    if (t < NT - 2)
      asm volatile("s_waitcnt vmcnt(4)" ::: "memory");
    else if (t == NT - 2)
      asm volatile("s_waitcnt vmcnt(0)" ::: "memory");
    CFENCE; __builtin_amdgcn_s_barrier(); CFENCE;
    __builtin_amdgcn_s_setprio(1);
#pragma unroll
    for (int m = 0; m < 4; ++m)
#pragma unroll
      for (int n = 0; n < 4; ++n)
        acc[m + 4][n] =
            __builtin_amdgcn_mfma_f32_16x16x32_f16(af[m], bf[n], acc[m + 4][n], 0, 0, 0);
    __builtin_amdgcn_s_setprio(0);
  }

  // epilogue; D mapping: col = lane&15, row = (lane>>4)*4 + i
  const int koff = half ? 1024 : 0;
  if (MODE == 0) {
    unsigned short* Tt = (unsigned short*)outp;
#pragma unroll
    for (int mi = 0; mi < 8; ++mi) {
      const int r = bm + wr * 128 + (mi >> 2) * 64 + (mi & 3) * 16 + (lane >> 4) * 4;
      const int b = r >> 11;
      const int rb = r & 2047;
#pragma unroll
      for (int n = 0; n < 4; ++n) {
        const int cpk = bn + wc * 64 + n * 16 + frc;
        const int ktrue = 2 * (cpk - koff) + (half ? 1 : 0);
        uint32 lo = f2h_bits(acc[mi][n][0]) | ((uint32)f2h_bits(acc[mi][n][1]) << 16);
        uint32 hi = f2h_bits(acc[mi][n][2]) | ((uint32)f2h_bits(acc[mi][n][3]) << 16);
        *(uint2*)&Tt[(size_t)b * 4194304 + (size_t)ktrue * 2048 + rb] =
            make_uint2(lo, hi);
      }
    }
  } else {
    float* out = (float*)outp + (size_t)z * 4194304;
#pragma unroll
    for (int mi = 0; mi < 8; ++mi) {
      const int p0 =
          bm + wr * 128 + (mi >> 2) * 64 + (mi & 3) * 16 + (lane >> 4) * 4 - koff;
#pragma unroll
      for (int n = 0; n < 4; ++n) {
        const int cg = bn + wc * 64 + n * 16 + frc;
#pragma unroll
        for (int i = 0; i < 4; ++i) {
          const int rtrue = 2 * (p0 + i) + (half ? 1 : 0);
          out[(size_t)rtrue * 2048 + cg] = acc[mi][n][i];
        }
      }
    }
  }
}

extern "C" void kernel_launch(void* const* d_in, const int* in_sizes, int n_in,
                              void* d_out, int out_size, void* d_ws,
                              size_t ws_size, hipStream_t stream) {
  const float* x = (const float*)d_in[0];
  float* out = (float*)d_out;

  // workspace (f16 elems): Xf/U2 33554432 | Ce 1048576 | Co 1048576 | Tt 33554432
  unsigned short* Xf = (unsigned short*)d_ws;  // aliased as U2 after GEMM1
  unsigned short* Ce = Xf + 33554432u;
  unsigned short* Co = Ce + 1048576u;
  unsigned short* Tt = Co + 1048576u;

  cvt_fold1<<<8192, 256, 0, stream>>>(x, Xf);
  gen_cos2<<<4096, 256, 0, stream>>>(Ce, Co);
  // stage 1: T[m][k] over folded K=1024; writes Tt[b][k_true][m] (f16)
  dct_gemm<0><<<dim3(8, 64, 1), 512, 0, stream>>>(Ce, Co, Xf, (void*)Tt);
  // stage 2 fold along m (Xf region reused as U2)
  fold2<<<8192, 256, 0, stream>>>(Tt, Xf);
  // stage 2: out[b] rows parity-unpacked, fp32
  dct_gemm<1><<<dim3(8, 8, 8), 512, 0, stream>>>(Ce, Co, Xf, (void*)out);
}